// Round 5
// baseline (568.266 us; speedup 1.0000x reference)
//
#include <hip/hip_runtime.h>

typedef __bf16 bf16x8 __attribute__((ext_vector_type(8)));
typedef __bf16 bf16x4 __attribute__((ext_vector_type(4)));
typedef float  f32x4  __attribute__((ext_vector_type(4)));

#define BM 128
#define BN 128
#define BK 32
#define NBLK 512

// async global->LDS, 16B per lane. LDS dest must be wave-uniform base + lane*16.
__device__ __forceinline__ void gload_lds16(const __bf16* g, __bf16* l) {
  __builtin_amdgcn_global_load_lds(
      (const __attribute__((address_space(1))) void*)g,
      (__attribute__((address_space(3))) void*)l,
      16, 0, 0);
}

// Software grid barrier: monotonic-epoch counter, device scope.
// All 512 blocks are co-resident (2/CU by capacity), so spinning is safe.
__device__ __forceinline__ void grid_bar(unsigned* ctr, unsigned epoch) {
  __syncthreads();                 // block's vmem drained (waitcnt before s_barrier)
  if (threadIdx.x == 0) {
    __threadfence();               // release: L2 writeback for cross-XCD visibility
    __hip_atomic_fetch_add(ctr, 1u, __ATOMIC_RELEASE, __HIP_MEMORY_SCOPE_AGENT);
    while (__hip_atomic_load(ctr, __ATOMIC_RELAXED, __HIP_MEMORY_SCOPE_AGENT) <
           epoch * NBLK) {
      __builtin_amdgcn_s_sleep(8);
    }
    __threadfence();               // acquire: invalidate stale L1/L2 lines
  }
  __syncthreads();
}

// One 128x128 GEMM tile: C[m,n] = sum_k A[m,k]*B[n,k] (both K-contiguous).
// 4 waves x (64x64 via 4x4 mfma_f32_16x16x32_bf16).
// MODE 0: QK epilogue (bias + bf16 split store by gn>>10)
// MODE 1: VT epilogue (bias0[gm] + bf16 store Vt[b][gm][s], gn = b*2048+s)
// MODE 2: plain fp32 C store
template<int MODE>
__device__ __forceinline__ void gemm_tile(
    const __bf16* __restrict__ Ap, const __bf16* __restrict__ Bp,
    float* __restrict__ C, int lda, int ldb, int ldc, int K,
    int bm0, int bn0,
    const float* __restrict__ bias0, const float* __restrict__ bias1,
    __bf16* __restrict__ out0, __bf16* __restrict__ out1,
    __bf16* As, __bf16* Bs)
{
  const int tid  = threadIdx.x;
  const int wave = tid >> 6;
  const int lane = tid & 63;
  const int quad = lane >> 4;
  const int l15  = lane & 15;
  const int wm   = (wave >> 1) * 64;
  const int wn   = (wave & 1) * 64;

  f32x4 acc[4][4];
#pragma unroll
  for (int i = 0; i < 4; ++i)
#pragma unroll
    for (int j = 0; j < 4; ++j)
      acc[i][j] = (f32x4){0.f, 0.f, 0.f, 0.f};

  // staging: 128x32 bf16 = 8KB per tile; 256 threads x 16B x 2 chunks
  const int l0 = tid * 8;
  const int l1 = (256 + tid) * 8;
  const int r0 = l0 >> 5, c0 = l0 & 31;
  const int r1 = l1 >> 5, c1 = l1 & 31;
  const __bf16* Ag0 = Ap + (size_t)(bm0 + r0) * lda + c0;
  const __bf16* Ag1 = Ap + (size_t)(bm0 + r1) * lda + c1;
  const __bf16* Bg0 = Bp + (size_t)(bn0 + r0) * ldb + c0;
  const __bf16* Bg1 = Bp + (size_t)(bn0 + r1) * ldb + c1;

  for (int k0 = 0; k0 < K; k0 += BK) {
    gload_lds16(Ag0 + k0, &As[l0]);
    gload_lds16(Ag1 + k0, &As[l1]);
    gload_lds16(Bg0 + k0, &Bs[l0]);
    gload_lds16(Bg1 + k0, &Bs[l1]);
    __syncthreads();

    bf16x8 af[4], bfv[4];
#pragma unroll
    for (int i = 0; i < 4; ++i)
      af[i] = *(const bf16x8*)&As[(wm + i * 16 + l15) * BK + quad * 8];
#pragma unroll
    for (int i = 0; i < 4; ++i)
      bfv[i] = *(const bf16x8*)&Bs[(wn + i * 16 + l15) * BK + quad * 8];

#pragma unroll
    for (int mi = 0; mi < 4; ++mi)
#pragma unroll
      for (int ni = 0; ni < 4; ++ni)
        acc[mi][ni] = __builtin_amdgcn_mfma_f32_16x16x32_bf16(
            af[mi], bfv[ni], acc[mi][ni], 0, 0, 0);
    __syncthreads();
  }

  // Epilogue. C/D layout (verified m89/m91): row m = quad*4+r, col n = lane&15.
#pragma unroll
  for (int mi = 0; mi < 4; ++mi) {
#pragma unroll
    for (int ni = 0; ni < 4; ++ni) {
      const int gn = bn0 + wn + ni * 16 + l15;
#pragma unroll
      for (int r = 0; r < 4; ++r) {
        const int gm = bm0 + wm + mi * 16 + quad * 4 + r;
        float v = acc[mi][ni][r];
        if (MODE == 0) {
          const int mat = gn >> 10;          // uniform per tile
          const int d   = gn & 1023;
          const float* bias = (mat == 0) ? bias0 : bias1;
          __bf16* dst = (mat == 0) ? out0 : out1;
          dst[(size_t)gm * 1024 + d] = (__bf16)(v + bias[d]);
        } else if (MODE == 1) {
          const int b = gn >> 11, s = gn & 2047;
          out0[(size_t)b * (1024 * 2048) + (size_t)gm * 2048 + s] =
              (__bf16)(v + bias0[gm]);
        } else {
          C[(size_t)gm * ldc + gn] = v;
        }
      }
    }
  }
}

// Softmax over one row of 2048 fp32 scores; bf16 weights written in-place.
__device__ __forceinline__ void softmax_row(float* __restrict__ row, float* red) {
  __bf16* wrow = (__bf16*)row;
  const int t = threadIdx.x;
  const int wave = t >> 6;
  const int lane = t & 63;
  float* redm = red;       // 4 floats
  float* reds = red + 4;   // 4 floats

  float4 a = ((const float4*)row)[t];
  float4 b = ((const float4*)row)[t + 256];
  const float sc = 0.03125f;  // 1/sqrt(1024)
  float x0 = a.x * sc, x1 = a.y * sc, x2 = a.z * sc, x3 = a.w * sc;
  float x4 = b.x * sc, x5 = b.y * sc, x6 = b.z * sc, x7 = b.w * sc;

  float mx = fmaxf(fmaxf(fmaxf(x0, x1), fmaxf(x2, x3)),
                   fmaxf(fmaxf(x4, x5), fmaxf(x6, x7)));
#pragma unroll
  for (int off = 32; off > 0; off >>= 1)
    mx = fmaxf(mx, __shfl_down(mx, off));
  if (lane == 0) redm[wave] = mx;
  __syncthreads();
  mx = fmaxf(fmaxf(redm[0], redm[1]), fmaxf(redm[2], redm[3]));

  float e0 = __expf(x0 - mx), e1 = __expf(x1 - mx);
  float e2 = __expf(x2 - mx), e3 = __expf(x3 - mx);
  float e4 = __expf(x4 - mx), e5 = __expf(x5 - mx);
  float e6 = __expf(x6 - mx), e7 = __expf(x7 - mx);
  float s = ((e0 + e1) + (e2 + e3)) + ((e4 + e5) + (e6 + e7));
#pragma unroll
  for (int off = 32; off > 0; off >>= 1)
    s += __shfl_down(s, off);
  if (lane == 0) reds[wave] = s;
  __syncthreads();
  const float rinv = 1.0f / (((reds[0] + reds[1]) + (reds[2] + reds[3])));

  bf16x4 w0, w1;
  w0[0] = (__bf16)(e0 * rinv); w0[1] = (__bf16)(e1 * rinv);
  w0[2] = (__bf16)(e2 * rinv); w0[3] = (__bf16)(e3 * rinv);
  w1[0] = (__bf16)(e4 * rinv); w1[1] = (__bf16)(e5 * rinv);
  w1[2] = (__bf16)(e6 * rinv); w1[3] = (__bf16)(e7 * rinv);
  ((bf16x4*)wrow)[t] = w0;
  ((bf16x4*)wrow)[t + 256] = w1;
  __syncthreads();  // protect red[] reuse by next row iteration
}

// Persistent kernel: 512 blocks x 256 threads = 2 blocks/CU (co-resident by
// capacity; 56 VGPR / 16KB LDS leave huge margin). Phases separated by
// software grid barrier. Per-phase tilings = round-2 separate-kernel config.
__global__ __launch_bounds__(256, 2)
void attn_mega(const float* __restrict__ x, const float* __restrict__ Wq,
               const float* __restrict__ Wk, const float* __restrict__ Wv,
               const float* __restrict__ bq, const float* __restrict__ bk,
               const float* __restrict__ bv, float* __restrict__ out,
               char* __restrict__ ws)
{
  // ws layout (112 MiB):
  //  [0,16M)   Q    bf16 [8192][1024]
  //  [16,32M)  K    bf16 [8192][1024]
  //  [32,48M)  Vt   bf16 [4][1024][2048]
  //  [48,64M)  xb   bf16 (proj phase only)
  //  [64,68M)  Wqk  bf16 [2048][1024] (proj phase only)
  //  [68,70M)  Wvb  bf16 [1024][1024] (proj phase only)
  //  [48,112M) Sc   fp32 [4][2048][2048]  (aliases xb/Wqk/Wvb; written phase 2)
  //  counter A: last 128B of Sc (untouched in phases 0-1; memset pre-launch)
  //  counter B: last 128B of d_out (untouched until phase 4; memset pre-launch)
  __bf16* Q    = (__bf16*)(ws);
  __bf16* Kb   = (__bf16*)(ws + (16ull << 20));
  __bf16* Vt   = (__bf16*)(ws + (32ull << 20));
  __bf16* xb   = (__bf16*)(ws + (48ull << 20));
  __bf16* Wqk  = (__bf16*)(ws + (64ull << 20));
  __bf16* Wvb  = (__bf16*)(ws + (68ull << 20));
  float*  Sc   = (float*)(ws + (48ull << 20));
  unsigned* ctrA = (unsigned*)(ws + (112ull << 20) - 128);
  unsigned* ctrB = (unsigned*)((char*)out + (32ull << 20) - 128);

  __shared__ __align__(16) __bf16 As[BM * BK];
  __shared__ __align__(16) __bf16 Bs[BN * BK];

  // ---- Phase 0: fp32 -> bf16 (x: units [0,8192); weights: [8192,11264)) ----
  for (int u = blockIdx.x; u < 11264; u += NBLK) {
    const float* src; __bf16* dst; int i;
    if (u < 8192) {
      src = x; dst = xb; i = u * 256 + threadIdx.x;
    } else {
      const int b = u - 8192;
      const int mat = b >> 10;
      i = (b & 1023) * 256 + threadIdx.x;
      src = (mat == 0) ? Wq : (mat == 1) ? Wk : Wv;
      dst = (mat == 0) ? Wqk : (mat == 1) ? (Wqk + 1048576) : Wvb;
    }
    float4 v = ((const float4*)src)[i];
    bf16x4 o;
    o[0] = (__bf16)v.x; o[1] = (__bf16)v.y; o[2] = (__bf16)v.z; o[3] = (__bf16)v.w;
    ((bf16x4*)dst)[i] = o;
  }
  grid_bar(ctrA, 1);

  // ---- Phase 1: projections. QK tiles [0,1024) (64x16), VT [1024,1536) (8x64)
  for (int t = blockIdx.x; t < 1536; t += NBLK) {
    if (t < 1024) {
      gemm_tile<0>(xb, Wqk, nullptr, 1024, 1024, 0, 1024,
                   (t & 63) * BM, (t >> 6) * BN, bq, bk, Q, Kb, As, Bs);
    } else {
      const int g = t - 1024;
      gemm_tile<1>(Wvb, xb, nullptr, 1024, 1024, 0, 1024,
                   (g & 7) * BM, (g >> 3) * BN, bv, nullptr, Vt, nullptr, As, Bs);
    }
  }
  grid_bar(ctrA, 2);

  // ---- Phase 2: scores = Q K^T, per batch z; 1024 tiles (16x16x4) ----
  for (int t = blockIdx.x; t < 1024; t += NBLK) {
    const int z = t >> 8, rem = t & 255;
    gemm_tile<2>(Q + (size_t)z * 2048 * 1024, Kb + (size_t)z * 2048 * 1024,
                 Sc + (size_t)z * 2048 * 2048, 1024, 1024, 2048, 1024,
                 (rem & 15) * BM, (rem >> 4) * BN,
                 nullptr, nullptr, nullptr, nullptr, As, Bs);
  }
  grid_bar(ctrB, 1);

  // ---- Phase 3: softmax, 8192 rows ----
  for (int r = blockIdx.x; r < 8192; r += NBLK)
    softmax_row(Sc + (size_t)r * 2048, (float*)As);
  grid_bar(ctrB, 2);

  // ---- Phase 4: O = W V^T^T; 512 tiles (16x8x4, 128x128) ----
  for (int t = blockIdx.x; t < 512; t += NBLK) {
    const int z = t >> 7, rem = t & 127;
    gemm_tile<2>((const __bf16*)Sc + (size_t)z * 2048 * 4096,
                 Vt + (size_t)z * 1024 * 2048,
                 out + (size_t)z * 2048 * 1024, 4096, 2048, 1024, 2048,
                 (rem & 15) * BM, (rem >> 4) * BN,
                 nullptr, nullptr, nullptr, nullptr, As, Bs);
  }
}

extern "C" void kernel_launch(void* const* d_in, const int* in_sizes, int n_in,
                              void* d_out, int out_size, void* d_ws, size_t ws_size,
                              hipStream_t stream) {
  const float* x  = (const float*)d_in[0];
  const float* Wq = (const float*)d_in[1];
  const float* bq = (const float*)d_in[2];
  const float* Wk = (const float*)d_in[3];
  const float* bk = (const float*)d_in[4];
  const float* Wv = (const float*)d_in[5];
  const float* bv = (const float*)d_in[6];
  float* out = (float*)d_out;
  char* ws = (char*)d_ws;

  // Zero the two barrier counters (ws/d_out are 0xAA-poisoned pre-launch).
  hipMemsetAsync(ws + (112ull << 20) - 128, 0, 128, stream);
  hipMemsetAsync((char*)out + (32ull << 20) - 128, 0, 128, stream);

  attn_mega<<<dim3(NBLK), dim3(256), 0, stream>>>(
      x, Wq, Wk, Wv, bq, bk, bv, out, ws);
}

// Round 6
// 278.256 us; speedup vs baseline: 2.0422x; 2.0422x over previous
//
#include <hip/hip_runtime.h>

typedef __bf16    bf16x8 __attribute__((ext_vector_type(8)));
typedef __bf16    bf16x4 __attribute__((ext_vector_type(4)));
typedef _Float16  f16x8  __attribute__((ext_vector_type(8)));
typedef float     f32x4  __attribute__((ext_vector_type(4)));

#define BM 128
#define BN 128
#define BK 32

// async global->LDS, 16B per lane. LDS dest must be wave-uniform base + lane*16.
__device__ __forceinline__ void gload_lds16(const __bf16* g, __bf16* l) {
  __builtin_amdgcn_global_load_lds(
      (const __attribute__((address_space(1))) void*)g,
      (__attribute__((address_space(3))) void*)l,
      16, 0, 0);
}

// One launch converts x (8192 blocks) + Wq/Wk/Wv (3072 blocks) to bf16.
__global__ void cvt_all(const float* __restrict__ x, const float* __restrict__ Wq,
                        const float* __restrict__ Wk, const float* __restrict__ Wv,
                        __bf16* __restrict__ xb, __bf16* __restrict__ Wqk,
                        __bf16* __restrict__ Wvb) {
  int b = blockIdx.x;
  const float* src;
  __bf16* dst;
  int i;
  if (b < 8192) {
    src = x; dst = xb; i = b * 256 + threadIdx.x;
  } else {
    b -= 8192;
    const int mat = b >> 10;
    i = (b & 1023) * 256 + threadIdx.x;
    src = (mat == 0) ? Wq : (mat == 1) ? Wk : Wv;
    dst = (mat == 0) ? Wqk : (mat == 1) ? (Wqk + 1048576) : Wvb;
  }
  float4 v = ((const float4*)src)[i];
  bf16x4 o;
  o[0] = (__bf16)v.x; o[1] = (__bf16)v.y; o[2] = (__bf16)v.z; o[3] = (__bf16)v.w;
  ((bf16x4*)dst)[i] = o;
}

// C[m,n] = sum_k A[m,k]*B[n,k]  (both K-contiguous). 128x128 tile, BK=32,
// 4 waves each computing 64x64 via 4x4 mfma_f32_16x16x32_bf16.
// MODE 0: QK epilogue  — bias + bf16 store, split by gn>>10 to Q / K row-major
// MODE 1: VT epilogue  — bias0[gm] + bf16 store to Vt[b][gm][s], gn = b*2048+s
// MODE 2: scores       — fp16 store of v/32 (scale folded in), ldc/sC in fp16 elts
template<int MODE>
__global__ __launch_bounds__(256, 2)
void gemm_bt(const __bf16* __restrict__ A, const __bf16* __restrict__ B,
             void* __restrict__ C,
             int lda, int ldb, int ldc, int K,
             long sA, long sB, long sC,
             const float* __restrict__ bias0, const float* __restrict__ bias1,
             __bf16* __restrict__ out0, __bf16* __restrict__ out1)
{
  A += (long)blockIdx.z * sA;
  B += (long)blockIdx.z * sB;

  const int tid  = threadIdx.x;
  const int wave = tid >> 6;
  const int lane = tid & 63;
  const int quad = lane >> 4;
  const int l15  = lane & 15;
  const int bm0  = blockIdx.x * BM;
  const int bn0  = blockIdx.y * BN;
  const int wm   = (wave >> 1) * 64;
  const int wn   = (wave & 1) * 64;

  __shared__ __align__(16) __bf16 As[BM * BK];
  __shared__ __align__(16) __bf16 Bs[BN * BK];

  f32x4 acc[4][4];
#pragma unroll
  for (int i = 0; i < 4; ++i)
#pragma unroll
    for (int j = 0; j < 4; ++j)
      acc[i][j] = (f32x4){0.f, 0.f, 0.f, 0.f};

  // staging: 128x32 bf16 = 8KB per tile; 256 threads x 16B x 2 chunks
  const int l0 = tid * 8;
  const int l1 = (256 + tid) * 8;
  const int r0 = l0 >> 5, c0 = l0 & 31;
  const int r1 = l1 >> 5, c1 = l1 & 31;
  const __bf16* Ag0 = A + (size_t)(bm0 + r0) * lda + c0;
  const __bf16* Ag1 = A + (size_t)(bm0 + r1) * lda + c1;
  const __bf16* Bg0 = B + (size_t)(bn0 + r0) * ldb + c0;
  const __bf16* Bg1 = B + (size_t)(bn0 + r1) * ldb + c1;

  for (int k0 = 0; k0 < K; k0 += BK) {
    gload_lds16(Ag0 + k0, &As[l0]);
    gload_lds16(Ag1 + k0, &As[l1]);
    gload_lds16(Bg0 + k0, &Bs[l0]);
    gload_lds16(Bg1 + k0, &Bs[l1]);
    __syncthreads();

    bf16x8 af[4], bfv[4];
#pragma unroll
    for (int i = 0; i < 4; ++i)
      af[i] = *(const bf16x8*)&As[(wm + i * 16 + l15) * BK + quad * 8];
#pragma unroll
    for (int i = 0; i < 4; ++i)
      bfv[i] = *(const bf16x8*)&Bs[(wn + i * 16 + l15) * BK + quad * 8];

#pragma unroll
    for (int mi = 0; mi < 4; ++mi)
#pragma unroll
      for (int ni = 0; ni < 4; ++ni)
        acc[mi][ni] = __builtin_amdgcn_mfma_f32_16x16x32_bf16(
            af[mi], bfv[ni], acc[mi][ni], 0, 0, 0);
    __syncthreads();
  }

  // Epilogue. C/D layout (verified m89/m91): row m = quad*4+r, col n = lane&15.
#pragma unroll
  for (int mi = 0; mi < 4; ++mi) {
#pragma unroll
    for (int ni = 0; ni < 4; ++ni) {
      const int gn = bn0 + wn + ni * 16 + l15;
#pragma unroll
      for (int r = 0; r < 4; ++r) {
        const int gm = bm0 + wm + mi * 16 + quad * 4 + r;
        float v = acc[mi][ni][r];
        if (MODE == 0) {
          const int mat = gn >> 10;          // uniform per tile (BN divides 1024)
          const int d   = gn & 1023;
          const float* bias = (mat == 0) ? bias0 : bias1;
          __bf16* dst = (mat == 0) ? out0 : out1;
          dst[(size_t)gm * 1024 + d] = (__bf16)(v + bias[d]);
        } else if (MODE == 1) {
          const int b = gn >> 11, s = gn & 2047;
          out0[(size_t)b * (1024 * 2048) + (size_t)gm * 2048 + s] =
              (__bf16)(v + bias0[gm]);
        } else {
          // scores: store scaled fp16
          ((_Float16*)C)[(long)blockIdx.z * sC + (size_t)gm * ldc + gn] =
              (_Float16)(v * 0.03125f);
        }
      }
    }
  }
}

// PV GEMM: 128x64 tile (waves 2x2, each 64x32), BK=32, K=2048.
// Grid 16x16x4 = 1024 blocks -> 4 blocks/CU (PV at 512/2 was occupancy-starved).
__global__ __launch_bounds__(256, 4)
void gemm_pv(const __bf16* __restrict__ A, const __bf16* __restrict__ B,
             float* __restrict__ C,
             int lda, int ldb, int ldc, int K, long sA, long sB, long sC)
{
  A += (long)blockIdx.z * sA;
  B += (long)blockIdx.z * sB;

  const int tid  = threadIdx.x;
  const int wave = tid >> 6;
  const int lane = tid & 63;
  const int quad = lane >> 4;
  const int l15  = lane & 15;
  const int bm0  = blockIdx.x * 128;
  const int bn0  = blockIdx.y * 64;
  const int wm   = (wave >> 1) * 64;
  const int wn   = (wave & 1) * 32;

  __shared__ __align__(16) __bf16 As[128 * BK];
  __shared__ __align__(16) __bf16 Bs[64 * BK];

  f32x4 acc[4][2];
#pragma unroll
  for (int i = 0; i < 4; ++i)
#pragma unroll
    for (int j = 0; j < 2; ++j)
      acc[i][j] = (f32x4){0.f, 0.f, 0.f, 0.f};

  // staging: A 128x32 (2 chunks of 16B/lane), B 64x32 (1 chunk)
  const int l0 = tid * 8;
  const int l1 = (256 + tid) * 8;
  const int r0 = l0 >> 5, c0 = l0 & 31;
  const int r1 = l1 >> 5, c1 = l1 & 31;
  const __bf16* Ag0 = A + (size_t)(bm0 + r0) * lda + c0;
  const __bf16* Ag1 = A + (size_t)(bm0 + r1) * lda + c1;
  const __bf16* Bg0 = B + (size_t)(bn0 + r0) * ldb + c0;

  for (int k0 = 0; k0 < K; k0 += BK) {
    gload_lds16(Ag0 + k0, &As[l0]);
    gload_lds16(Ag1 + k0, &As[l1]);
    gload_lds16(Bg0 + k0, &Bs[l0]);
    __syncthreads();

    bf16x8 af[4], bfv[2];
#pragma unroll
    for (int i = 0; i < 4; ++i)
      af[i] = *(const bf16x8*)&As[(wm + i * 16 + l15) * BK + quad * 8];
#pragma unroll
    for (int i = 0; i < 2; ++i)
      bfv[i] = *(const bf16x8*)&Bs[(wn + i * 16 + l15) * BK + quad * 8];

#pragma unroll
    for (int mi = 0; mi < 4; ++mi)
#pragma unroll
      for (int ni = 0; ni < 2; ++ni)
        acc[mi][ni] = __builtin_amdgcn_mfma_f32_16x16x32_bf16(
            af[mi], bfv[ni], acc[mi][ni], 0, 0, 0);
    __syncthreads();
  }

#pragma unroll
  for (int mi = 0; mi < 4; ++mi) {
#pragma unroll
    for (int ni = 0; ni < 2; ++ni) {
      const int gn = bn0 + wn + ni * 16 + l15;
#pragma unroll
      for (int r = 0; r < 4; ++r) {
        const int gm = bm0 + wm + mi * 16 + quad * 4 + r;
        C[(long)blockIdx.z * sC + (size_t)gm * ldc + gn] = acc[mi][ni][r];
      }
    }
  }
}

// One block per row of 2048 fp16 scores (already scaled by 1/32).
// Softmax; writes bf16 weights IN-PLACE (same 2B footprint, same offsets).
__global__ __launch_bounds__(256)
void softmax_rows(_Float16* __restrict__ S) {
  _Float16* row = S + (size_t)blockIdx.x * 2048;
  const int t = threadIdx.x;
  const int wave = t >> 6;
  const int lane = t & 63;
  __shared__ float redm[4];
  __shared__ float reds[4];

  f16x8 h = ((const f16x8*)row)[t];
  float x0 = (float)h[0], x1 = (float)h[1], x2 = (float)h[2], x3 = (float)h[3];
  float x4 = (float)h[4], x5 = (float)h[5], x6 = (float)h[6], x7 = (float)h[7];

  float mx = fmaxf(fmaxf(fmaxf(x0, x1), fmaxf(x2, x3)),
                   fmaxf(fmaxf(x4, x5), fmaxf(x6, x7)));
#pragma unroll
  for (int off = 32; off > 0; off >>= 1)
    mx = fmaxf(mx, __shfl_down(mx, off));
  if (lane == 0) redm[wave] = mx;
  __syncthreads();
  mx = fmaxf(fmaxf(redm[0], redm[1]), fmaxf(redm[2], redm[3]));

  float e0 = __expf(x0 - mx), e1 = __expf(x1 - mx);
  float e2 = __expf(x2 - mx), e3 = __expf(x3 - mx);
  float e4 = __expf(x4 - mx), e5 = __expf(x5 - mx);
  float e6 = __expf(x6 - mx), e7 = __expf(x7 - mx);
  float s = ((e0 + e1) + (e2 + e3)) + ((e4 + e5) + (e6 + e7));
#pragma unroll
  for (int off = 32; off > 0; off >>= 1)
    s += __shfl_down(s, off);
  if (lane == 0) reds[wave] = s;
  __syncthreads();
  const float rinv = 1.0f / (((reds[0] + reds[1]) + (reds[2] + reds[3])));

  bf16x8 w;
  w[0] = (__bf16)(e0 * rinv); w[1] = (__bf16)(e1 * rinv);
  w[2] = (__bf16)(e2 * rinv); w[3] = (__bf16)(e3 * rinv);
  w[4] = (__bf16)(e4 * rinv); w[5] = (__bf16)(e5 * rinv);
  w[6] = (__bf16)(e6 * rinv); w[7] = (__bf16)(e7 * rinv);
  // all reads happened before the barriers above; in-place write is safe
  ((bf16x8*)row)[t] = w;
}

extern "C" void kernel_launch(void* const* d_in, const int* in_sizes, int n_in,
                              void* d_out, int out_size, void* d_ws, size_t ws_size,
                              hipStream_t stream) {
  const float* x  = (const float*)d_in[0];
  const float* Wq = (const float*)d_in[1];
  const float* bq = (const float*)d_in[2];
  const float* Wk = (const float*)d_in[3];
  const float* bk = (const float*)d_in[4];
  const float* Wv = (const float*)d_in[5];
  const float* bv = (const float*)d_in[6];
  float* out = (float*)d_out;

  // ws layout (80 MiB used):
  //  [0,16M)   Q    bf16 [8192][1024]
  //  [16,32M)  K    bf16 [8192][1024]
  //  [32,48M)  Vt   bf16 [4][1024][2048]
  //  [48,64M)  xb   bf16 (projection phase only)
  //  [64,68M)  Wqk  bf16 [2048][1024] (projection phase only)
  //  [68,70M)  Wvb  bf16 [1024][1024] (projection phase only)
  //  [48,80M)  Sc   fp16 [4][2048][2048]  (aliases xb/Wqk/Wvb; written later)
  char* ws = (char*)d_ws;
  __bf16*   Q    = (__bf16*)(ws);
  __bf16*   Kb   = (__bf16*)(ws + (16ull << 20));
  __bf16*   Vt   = (__bf16*)(ws + (32ull << 20));
  __bf16*   xb   = (__bf16*)(ws + (48ull << 20));
  __bf16*   Wqk  = (__bf16*)(ws + (64ull << 20));
  __bf16*   Wvb  = (__bf16*)(ws + (68ull << 20));
  _Float16* Sc   = (_Float16*)(ws + (48ull << 20));

  dim3 blk(256);

  // fp32 -> bf16, one launch
  cvt_all<<<11264, blk, 0, stream>>>(x, Wq, Wk, Wv, xb, Wqk, Wvb);

  // QK: [8192,1024] @ [2048,1024]^T -> Q, K (bf16, +bias)
  gemm_bt<0><<<dim3(64, 16, 1), blk, 0, stream>>>(
      xb, Wqk, nullptr, 1024, 1024, 0, 1024,
      0L, 0L, 0L, bq, bk, Q, Kb);

  // VT: Wv[1024,1024] @ xb[8192,1024]^T -> Vt[b][d][s] (bf16, +bias[d])
  gemm_bt<1><<<dim3(8, 64, 1), blk, 0, stream>>>(
      Wvb, xb, nullptr, 1024, 1024, 0, 1024,
      0L, 0L, 0L, bv, nullptr, Vt, nullptr);

  // scores: per batch Q[2048,1024] @ K[2048,1024]^T -> fp16 [2048,2048], /32
  gemm_bt<2><<<dim3(16, 16, 4), blk, 0, stream>>>(
      Q, Kb, Sc, 1024, 1024, 2048, 1024,
      2048L * 1024, 2048L * 1024, 2048L * 2048,
      nullptr, nullptr, nullptr, nullptr);

  softmax_rows<<<8192, blk, 0, stream>>>(Sc);

  // PV: per batch weights(bf16, lda=2048) [2048,2048] @ Vt[1024,2048]^T -> out fp32
  gemm_pv<<<dim3(16, 16, 4), blk, 0, stream>>>(
      (const __bf16*)Sc, Vt, out, 2048, 2048, 1024, 2048,
      2048L * 2048, 1024L * 2048, 2048L * 1024);
}

// Round 7
// 268.859 us; speedup vs baseline: 2.1136x; 1.0350x over previous
//
#include <hip/hip_runtime.h>

typedef __bf16    bf16x8 __attribute__((ext_vector_type(8)));
typedef __bf16    bf16x4 __attribute__((ext_vector_type(4)));
typedef float     f32x4  __attribute__((ext_vector_type(4)));

#define BM 128
#define BN 128
#define BK 32

// async global->LDS, 16B per lane. LDS dest must be wave-uniform base + lane*16.
__device__ __forceinline__ void gload_lds16(const __bf16* g, __bf16* l) {
  __builtin_amdgcn_global_load_lds(
      (const __attribute__((address_space(1))) void*)g,
      (__attribute__((address_space(3))) void*)l,
      16, 0, 0);
}

// One launch converts x (8192 blocks) + Wq/Wk/Wv (3072 blocks) to bf16.
// Block 0 additionally zero-inits the row-sum accumulator (stream-ordered
// well before the scores kernel needs it).
__global__ void cvt_all(const float* __restrict__ x, const float* __restrict__ Wq,
                        const float* __restrict__ Wk, const float* __restrict__ Wv,
                        __bf16* __restrict__ xb, __bf16* __restrict__ Wqk,
                        __bf16* __restrict__ Wvb, float* __restrict__ lsum) {
  int b = blockIdx.x;
  if (b == 0) {
    for (int j = threadIdx.x; j < 8192; j += 256) lsum[j] = 0.f;
  }
  const float* src;
  __bf16* dst;
  int i;
  if (b < 8192) {
    src = x; dst = xb; i = b * 256 + threadIdx.x;
  } else {
    b -= 8192;
    const int mat = b >> 10;
    i = (b & 1023) * 256 + threadIdx.x;
    src = (mat == 0) ? Wq : (mat == 1) ? Wk : Wv;
    dst = (mat == 0) ? Wqk : (mat == 1) ? (Wqk + 1048576) : Wvb;
  }
  float4 v = ((const float4*)src)[i];
  bf16x4 o;
  o[0] = (__bf16)v.x; o[1] = (__bf16)v.y; o[2] = (__bf16)v.z; o[3] = (__bf16)v.w;
  ((bf16x4*)dst)[i] = o;
}

// C[m,n] = sum_k A[m,k]*B[n,k]  (both K-contiguous). 128x128 tile, BK=32,
// 4 waves each computing 64x64 via 4x4 mfma_f32_16x16x32_bf16.
// MODE 0: QK epilogue  — bias + bf16 store, split by gn>>10 to Q / K row-major
// MODE 1: VT epilogue  — bias0[gm] + bf16 store to Vt[b][gm][s], gn = b*2048+s
// MODE 2: scores       — e = exp(v/32) stored bf16 (unnormalized softmax
//                        weights) + per-row sum atomicAdd into lsum
// MODE 3: PV           — fp32 store of acc * (1/lsum[row]) (normalization)
template<int MODE>
__global__ __launch_bounds__(256, 2)
void gemm_bt(const __bf16* __restrict__ A, const __bf16* __restrict__ B,
             float* __restrict__ C,
             int lda, int ldb, int ldc, int K,
             long sA, long sB, long sC,
             const float* __restrict__ bias0, const float* __restrict__ bias1,
             float* __restrict__ lsum,
             __bf16* __restrict__ out0, __bf16* __restrict__ out1)
{
  A += (long)blockIdx.z * sA;
  B += (long)blockIdx.z * sB;

  const int tid  = threadIdx.x;
  const int wave = tid >> 6;
  const int lane = tid & 63;
  const int quad = lane >> 4;
  const int l15  = lane & 15;
  const int bm0  = blockIdx.x * BM;
  const int bn0  = blockIdx.y * BN;
  const int wm   = (wave >> 1) * 64;
  const int wn   = (wave & 1) * 64;

  __shared__ __align__(16) __bf16 As[BM * BK];
  __shared__ __align__(16) __bf16 Bs[BN * BK];

  f32x4 acc[4][4];
#pragma unroll
  for (int i = 0; i < 4; ++i)
#pragma unroll
    for (int j = 0; j < 4; ++j)
      acc[i][j] = (f32x4){0.f, 0.f, 0.f, 0.f};

  // staging: 128x32 bf16 = 8KB per tile; 256 threads x 16B x 2 chunks
  const int l0 = tid * 8;
  const int l1 = (256 + tid) * 8;
  const int r0 = l0 >> 5, c0 = l0 & 31;
  const int r1 = l1 >> 5, c1 = l1 & 31;
  const __bf16* Ag0 = A + (size_t)(bm0 + r0) * lda + c0;
  const __bf16* Ag1 = A + (size_t)(bm0 + r1) * lda + c1;
  const __bf16* Bg0 = B + (size_t)(bn0 + r0) * ldb + c0;
  const __bf16* Bg1 = B + (size_t)(bn0 + r1) * ldb + c1;

  for (int k0 = 0; k0 < K; k0 += BK) {
    gload_lds16(Ag0 + k0, &As[l0]);
    gload_lds16(Ag1 + k0, &As[l1]);
    gload_lds16(Bg0 + k0, &Bs[l0]);
    gload_lds16(Bg1 + k0, &Bs[l1]);
    __syncthreads();

    bf16x8 af[4], bfv[4];
#pragma unroll
    for (int i = 0; i < 4; ++i)
      af[i] = *(const bf16x8*)&As[(wm + i * 16 + l15) * BK + quad * 8];
#pragma unroll
    for (int i = 0; i < 4; ++i)
      bfv[i] = *(const bf16x8*)&Bs[(wn + i * 16 + l15) * BK + quad * 8];

#pragma unroll
    for (int mi = 0; mi < 4; ++mi)
#pragma unroll
      for (int ni = 0; ni < 4; ++ni)
        acc[mi][ni] = __builtin_amdgcn_mfma_f32_16x16x32_bf16(
            af[mi], bfv[ni], acc[mi][ni], 0, 0, 0);
    __syncthreads();
  }

  // Epilogue. C/D layout (verified m89/m91): row m = quad*4+r, col n = lane&15.
  if (MODE == 2) {
    // scores: w = exp(v/32) -> bf16; row sums into lsum via shfl+atomic.
#pragma unroll
    for (int mi = 0; mi < 4; ++mi) {
#pragma unroll
      for (int r = 0; r < 4; ++r) {
        const int gm = bm0 + wm + mi * 16 + quad * 4 + r;
        float part = 0.f;
#pragma unroll
        for (int ni = 0; ni < 4; ++ni) {
          const int gn = bn0 + wn + ni * 16 + l15;
          const __bf16 eb = (__bf16)__expf(acc[mi][ni][r] * 0.03125f);
          out0[(long)blockIdx.z * sC + (size_t)gm * ldc + gn] = eb;
          part += (float)eb;  // sum the rounded values PV will actually read
        }
        part += __shfl_xor(part, 1);
        part += __shfl_xor(part, 2);
        part += __shfl_xor(part, 4);
        part += __shfl_xor(part, 8);
        if (l15 == 0)
          atomicAdd(&lsum[blockIdx.z * 2048 + gm], part);
      }
    }
  } else if (MODE == 3) {
    // PV: normalize by row sum while storing fp32.
#pragma unroll
    for (int mi = 0; mi < 4; ++mi) {
#pragma unroll
      for (int r = 0; r < 4; ++r) {
        const int gm = bm0 + wm + mi * 16 + quad * 4 + r;
        const float rv = 1.0f / lsum[blockIdx.z * 2048 + gm];
#pragma unroll
        for (int ni = 0; ni < 4; ++ni) {
          const int gn = bn0 + wn + ni * 16 + l15;
          C[(long)blockIdx.z * sC + (size_t)gm * ldc + gn] = acc[mi][ni][r] * rv;
        }
      }
    }
  } else {
#pragma unroll
    for (int mi = 0; mi < 4; ++mi) {
#pragma unroll
      for (int ni = 0; ni < 4; ++ni) {
        const int gn = bn0 + wn + ni * 16 + l15;
#pragma unroll
        for (int r = 0; r < 4; ++r) {
          const int gm = bm0 + wm + mi * 16 + quad * 4 + r;
          float v = acc[mi][ni][r];
          if (MODE == 0) {
            const int mat = gn >> 10;          // uniform per tile
            const int d   = gn & 1023;
            const float* bias = (mat == 0) ? bias0 : bias1;
            __bf16* dst = (mat == 0) ? out0 : out1;
            dst[(size_t)gm * 1024 + d] = (__bf16)(v + bias[d]);
          } else {  // MODE 1
            const int b = gn >> 11, s = gn & 2047;
            out0[(size_t)b * (1024 * 2048) + (size_t)gm * 2048 + s] =
                (__bf16)(v + bias0[gm]);
          }
        }
      }
    }
  }
}

extern "C" void kernel_launch(void* const* d_in, const int* in_sizes, int n_in,
                              void* d_out, int out_size, void* d_ws, size_t ws_size,
                              hipStream_t stream) {
  const float* x  = (const float*)d_in[0];
  const float* Wq = (const float*)d_in[1];
  const float* bq = (const float*)d_in[2];
  const float* Wk = (const float*)d_in[3];
  const float* bk = (const float*)d_in[4];
  const float* Wv = (const float*)d_in[5];
  const float* bv = (const float*)d_in[6];
  float* out = (float*)d_out;

  // ws layout:
  //  [0,16M)    Q    bf16 [8192][1024]
  //  [16,32M)   K    bf16 [8192][1024]
  //  [32,48M)   Vt   bf16 [4][1024][2048]
  //  [48,64M)   xb   bf16 (projection phase only)
  //  [64,68M)   Wqk  bf16 [2048][1024] (projection phase only)
  //  [68,70M)   Wvb  bf16 [1024][1024] (projection phase only)
  //  [48,80M)   Sc   bf16 [4][2048][2048] exp-weights (aliases xb/Wqk/Wvb)
  //  [110M,+32K) lsum fp32 [8192] row sums (zeroed by cvt_all block 0)
  char* ws = (char*)d_ws;
  __bf16* Q    = (__bf16*)(ws);
  __bf16* Kb   = (__bf16*)(ws + (16ull << 20));
  __bf16* Vt   = (__bf16*)(ws + (32ull << 20));
  __bf16* xb   = (__bf16*)(ws + (48ull << 20));
  __bf16* Wqk  = (__bf16*)(ws + (64ull << 20));
  __bf16* Wvb  = (__bf16*)(ws + (68ull << 20));
  __bf16* Sc   = (__bf16*)(ws + (48ull << 20));
  float*  lsum = (float*)(ws + (110ull << 20));

  dim3 blk(256);

  // fp32 -> bf16 (+ lsum zero-init), one launch
  cvt_all<<<11264, blk, 0, stream>>>(x, Wq, Wk, Wv, xb, Wqk, Wvb, lsum);

  // QK: [8192,1024] @ [2048,1024]^T -> Q, K (bf16, +bias)
  gemm_bt<0><<<dim3(64, 16, 1), blk, 0, stream>>>(
      xb, Wqk, nullptr, 1024, 1024, 0, 1024,
      0L, 0L, 0L, bq, bk, nullptr, Q, Kb);

  // VT: Wv[1024,1024] @ xb[8192,1024]^T -> Vt[b][d][s] (bf16, +bias[d])
  gemm_bt<1><<<dim3(8, 64, 1), blk, 0, stream>>>(
      Wvb, xb, nullptr, 1024, 1024, 0, 1024,
      0L, 0L, 0L, bv, nullptr, nullptr, Vt, nullptr);

  // scores: per batch Q[2048,1024] @ K[2048,1024]^T -> bf16 exp-weights + lsum
  gemm_bt<2><<<dim3(16, 16, 4), blk, 0, stream>>>(
      Q, Kb, nullptr, 1024, 1024, 2048, 1024,
      2048L * 1024, 2048L * 1024, 2048L * 2048,
      nullptr, nullptr, lsum, Sc, nullptr);

  // PV: per batch Sc[2048,2048](bf16) @ Vt[1024,2048]^T -> out fp32, /lsum
  gemm_bt<3><<<dim3(16, 8, 4), blk, 0, stream>>>(
      Sc, Vt, out, 2048, 2048, 1024, 2048,
      2048L * 2048, 1024L * 2048, 2048L * 1024,
      nullptr, nullptr, lsum, nullptr, nullptr);
}

// Round 8
// 235.863 us; speedup vs baseline: 2.4093x; 1.1399x over previous
//
#include <hip/hip_runtime.h>

typedef __bf16    bf16x8 __attribute__((ext_vector_type(8)));
typedef __bf16    bf16x4 __attribute__((ext_vector_type(4)));
typedef float     f32x4  __attribute__((ext_vector_type(4)));

#define BM 128
#define BN 128
#define BK 64

// async global->LDS, 16B per lane. LDS dest must be wave-uniform base + lane*16.
__device__ __forceinline__ void gload_lds16(const __bf16* g, __bf16* l) {
  __builtin_amdgcn_global_load_lds(
      (const __attribute__((address_space(1))) void*)g,
      (__attribute__((address_space(3))) void*)l,
      16, 0, 0);
}

// One launch converts x (8192 blocks) + Wq/Wk/Wv (3072 blocks) to bf16.
// Block 0 additionally zero-inits the row-sum accumulator.
__global__ void cvt_all(const float* __restrict__ x, const float* __restrict__ Wq,
                        const float* __restrict__ Wk, const float* __restrict__ Wv,
                        __bf16* __restrict__ xb, __bf16* __restrict__ Wqk,
                        __bf16* __restrict__ Wvb, float* __restrict__ lsum) {
  int b = blockIdx.x;
  if (b == 0) {
    for (int j = threadIdx.x; j < 8192; j += 256) lsum[j] = 0.f;
  }
  const float* src;
  __bf16* dst;
  int i;
  if (b < 8192) {
    src = x; dst = xb; i = b * 256 + threadIdx.x;
  } else {
    b -= 8192;
    const int mat = b >> 10;
    i = (b & 1023) * 256 + threadIdx.x;
    src = (mat == 0) ? Wq : (mat == 1) ? Wk : Wv;
    dst = (mat == 0) ? Wqk : (mat == 1) ? (Wqk + 1048576) : Wvb;
  }
  float4 v = ((const float4*)src)[i];
  bf16x4 o;
  o[0] = (__bf16)v.x; o[1] = (__bf16)v.y; o[2] = (__bf16)v.z; o[3] = (__bf16)v.w;
  ((bf16x4*)dst)[i] = o;
}

// C[m,n] = sum_k A[m,k]*B[n,k]  (both K-contiguous). 128x128 tile, BK=64
// (32 MFMA per barrier pair — halves the vmcnt(0)+s_barrier drain frequency
// vs BK=32). LDS tiles use an XOR-swizzle: 16B group g' of row r holds
// global k-group (g' ^ (r&7)), applied on the GLOBAL SOURCE address (the
// global_load_lds LDS dest is forced linear). Fragment reads then spread 8
// consecutive rows over all 32 banks -> 2 lanes/bank = conflict-free.
// MODE 0: QK epilogue  — bias + bf16 store, split by gn>>10 to Q / K row-major
// MODE 1: VT epilogue  — bias0[gm] + bf16 store to Vt[b][gm][s], gn = b*2048+s
// MODE 2: scores       — e = exp(v/32) stored bf16 + per-row sums into lsum
// MODE 3: PV           — fp32 store of acc * (1/lsum[row])
template<int MODE>
__global__ __launch_bounds__(256, 2)
void gemm_bt(const __bf16* __restrict__ A, const __bf16* __restrict__ B,
             float* __restrict__ C,
             int lda, int ldb, int ldc, int K,
             long sA, long sB, long sC,
             const float* __restrict__ bias0, const float* __restrict__ bias1,
             float* __restrict__ lsum,
             __bf16* __restrict__ out0, __bf16* __restrict__ out1)
{
  A += (long)blockIdx.z * sA;
  B += (long)blockIdx.z * sB;

  const int tid  = threadIdx.x;
  const int wave = tid >> 6;
  const int lane = tid & 63;
  const int quad = lane >> 4;
  const int l15  = lane & 15;
  const int bm0  = blockIdx.x * BM;
  const int bn0  = blockIdx.y * BN;
  const int wm   = (wave >> 1) * 64;
  const int wn   = (wave & 1) * 64;

  __shared__ __align__(16) __bf16 As[BM * BK];   // 16 KB
  __shared__ __align__(16) __bf16 Bs[BN * BK];   // 16 KB

  f32x4 acc[4][4];
#pragma unroll
  for (int i = 0; i < 4; ++i)
#pragma unroll
    for (int j = 0; j < 4; ++j)
      acc[i][j] = (f32x4){0.f, 0.f, 0.f, 0.f};

  // Staging: tile 128x64 bf16 = 16 KB = 4 chunks x (256 thr x 16 B).
  // Chunk c, thread tid -> LDS elements [c*2048 + tid*8, +8):
  //   row r = c*32 + (tid>>3), group g' = tid&7.
  // Global source applies the swizzle: k-group g = g' ^ (r&7).
  const __bf16* Ag[4];
  const __bf16* Bg[4];
#pragma unroll
  for (int c = 0; c < 4; ++c) {
    const int r  = c * 32 + (tid >> 3);
    const int g  = (tid & 7) ^ (r & 7);
    Ag[c] = A + (size_t)(bm0 + r) * lda + g * 8;
    Bg[c] = B + (size_t)(bn0 + r) * ldb + g * 8;
  }

  for (int k0 = 0; k0 < K; k0 += BK) {
#pragma unroll
    for (int c = 0; c < 4; ++c) {
      gload_lds16(Ag[c] + k0, &As[c * 2048 + tid * 8]);
      gload_lds16(Bg[c] + k0, &Bs[c * 2048 + tid * 8]);
    }
    __syncthreads();

#pragma unroll
    for (int kk = 0; kk < 2; ++kk) {
      bf16x8 af[4], bfv[4];
#pragma unroll
      for (int i = 0; i < 4; ++i) {
        const int R = wm + i * 16 + l15;
        af[i] = *(const bf16x8*)&As[R * BK + (((kk * 4 + quad) ^ (R & 7)) * 8)];
      }
#pragma unroll
      for (int i = 0; i < 4; ++i) {
        const int R = wn + i * 16 + l15;
        bfv[i] = *(const bf16x8*)&Bs[R * BK + (((kk * 4 + quad) ^ (R & 7)) * 8)];
      }
#pragma unroll
      for (int mi = 0; mi < 4; ++mi)
#pragma unroll
        for (int ni = 0; ni < 4; ++ni)
          acc[mi][ni] = __builtin_amdgcn_mfma_f32_16x16x32_bf16(
              af[mi], bfv[ni], acc[mi][ni], 0, 0, 0);
    }
    __syncthreads();
  }

  // Epilogue. C/D layout (verified m89/m91): row m = quad*4+r, col n = lane&15.
  if (MODE == 2) {
    // scores: w = exp(v/32) -> bf16; row sums into lsum via shfl+atomic.
#pragma unroll
    for (int mi = 0; mi < 4; ++mi) {
#pragma unroll
      for (int r = 0; r < 4; ++r) {
        const int gm = bm0 + wm + mi * 16 + quad * 4 + r;
        float part = 0.f;
#pragma unroll
        for (int ni = 0; ni < 4; ++ni) {
          const int gn = bn0 + wn + ni * 16 + l15;
          const __bf16 eb = (__bf16)__expf(acc[mi][ni][r] * 0.03125f);
          out0[(long)blockIdx.z * sC + (size_t)gm * ldc + gn] = eb;
          part += (float)eb;  // sum the rounded values PV will actually read
        }
        part += __shfl_xor(part, 1);
        part += __shfl_xor(part, 2);
        part += __shfl_xor(part, 4);
        part += __shfl_xor(part, 8);
        if (l15 == 0)
          atomicAdd(&lsum[blockIdx.z * 2048 + gm], part);
      }
    }
  } else if (MODE == 3) {
    // PV: normalize by row sum while storing fp32.
#pragma unroll
    for (int mi = 0; mi < 4; ++mi) {
#pragma unroll
      for (int r = 0; r < 4; ++r) {
        const int gm = bm0 + wm + mi * 16 + quad * 4 + r;
        const float rv = 1.0f / lsum[blockIdx.z * 2048 + gm];
#pragma unroll
        for (int ni = 0; ni < 4; ++ni) {
          const int gn = bn0 + wn + ni * 16 + l15;
          C[(long)blockIdx.z * sC + (size_t)gm * ldc + gn] = acc[mi][ni][r] * rv;
        }
      }
    }
  } else {
#pragma unroll
    for (int mi = 0; mi < 4; ++mi) {
#pragma unroll
      for (int ni = 0; ni < 4; ++ni) {
        const int gn = bn0 + wn + ni * 16 + l15;
#pragma unroll
        for (int r = 0; r < 4; ++r) {
          const int gm = bm0 + wm + mi * 16 + quad * 4 + r;
          float v = acc[mi][ni][r];
          if (MODE == 0) {
            const int mat = gn >> 10;          // uniform per tile
            const int d   = gn & 1023;
            const float* bias = (mat == 0) ? bias0 : bias1;
            __bf16* dst = (mat == 0) ? out0 : out1;
            dst[(size_t)gm * 1024 + d] = (__bf16)(v + bias[d]);
          } else {  // MODE 1
            const int b = gn >> 11, s = gn & 2047;
            out0[(size_t)b * (1024 * 2048) + (size_t)gm * 2048 + s] =
                (__bf16)(v + bias0[gm]);
          }
        }
      }
    }
  }
}

extern "C" void kernel_launch(void* const* d_in, const int* in_sizes, int n_in,
                              void* d_out, int out_size, void* d_ws, size_t ws_size,
                              hipStream_t stream) {
  const float* x  = (const float*)d_in[0];
  const float* Wq = (const float*)d_in[1];
  const float* bq = (const float*)d_in[2];
  const float* Wk = (const float*)d_in[3];
  const float* bk = (const float*)d_in[4];
  const float* Wv = (const float*)d_in[5];
  const float* bv = (const float*)d_in[6];
  float* out = (float*)d_out;

  // ws layout:
  //  [0,16M)    Q    bf16 [8192][1024]
  //  [16,32M)   K    bf16 [8192][1024]
  //  [32,48M)   Vt   bf16 [4][1024][2048]
  //  [48,64M)   xb   bf16 (projection phase only)
  //  [64,68M)   Wqk  bf16 [2048][1024] (projection phase only)
  //  [68,70M)   Wvb  bf16 [1024][1024] (projection phase only)
  //  [48,80M)   Sc   bf16 [4][2048][2048] exp-weights (aliases xb/Wqk/Wvb)
  //  [110M,+32K) lsum fp32 [8192] row sums (zeroed by cvt_all block 0)
  char* ws = (char*)d_ws;
  __bf16* Q    = (__bf16*)(ws);
  __bf16* Kb   = (__bf16*)(ws + (16ull << 20));
  __bf16* Vt   = (__bf16*)(ws + (32ull << 20));
  __bf16* xb   = (__bf16*)(ws + (48ull << 20));
  __bf16* Wqk  = (__bf16*)(ws + (64ull << 20));
  __bf16* Wvb  = (__bf16*)(ws + (68ull << 20));
  __bf16* Sc   = (__bf16*)(ws + (48ull << 20));
  float*  lsum = (float*)(ws + (110ull << 20));

  dim3 blk(256);

  // fp32 -> bf16 (+ lsum zero-init), one launch
  cvt_all<<<11264, blk, 0, stream>>>(x, Wq, Wk, Wv, xb, Wqk, Wvb, lsum);

  // QK: [8192,1024] @ [2048,1024]^T -> Q, K (bf16, +bias)
  gemm_bt<0><<<dim3(64, 16, 1), blk, 0, stream>>>(
      xb, Wqk, nullptr, 1024, 1024, 0, 1024,
      0L, 0L, 0L, bq, bk, nullptr, Q, Kb);

  // VT: Wv[1024,1024] @ xb[8192,1024]^T -> Vt[b][d][s] (bf16, +bias[d])
  gemm_bt<1><<<dim3(8, 64, 1), blk, 0, stream>>>(
      Wvb, xb, nullptr, 1024, 1024, 0, 1024,
      0L, 0L, 0L, bv, nullptr, nullptr, Vt, nullptr);

  // scores: per batch Q[2048,1024] @ K[2048,1024]^T -> bf16 exp-weights + lsum
  gemm_bt<2><<<dim3(16, 16, 4), blk, 0, stream>>>(
      Q, Kb, nullptr, 1024, 1024, 2048, 1024,
      2048L * 1024, 2048L * 1024, 2048L * 2048,
      nullptr, nullptr, lsum, Sc, nullptr);

  // PV: per batch Sc[2048,2048](bf16) @ Vt[1024,2048]^T -> out fp32, /lsum
  gemm_bt<3><<<dim3(16, 8, 4), blk, 0, stream>>>(
      Sc, Vt, out, 2048, 2048, 1024, 2048,
      2048L * 2048, 1024L * 2048, 2048L * 1024,
      nullptr, nullptr, lsum, nullptr, nullptr);
}